// Round 10
// baseline (258.309 us; speedup 1.0000x reference)
//
#include <hip/hip_runtime.h>
#include <math.h>

#define LL    1024
#define BB    16
#define NN1   2048      // 2*L
#define NNH   51200     // 50*L

using f32x2 = __attribute__((ext_vector_type(2))) float;

// ---------------- transpose X (16 x 1024) -> XT (1024 x 16) ----------------
__global__ void k_xt(const float* __restrict__ X, float* __restrict__ XT) {
    int id = blockIdx.x * 256 + threadIdx.x;     // 16384 total
    int n = id >> 4, b = id & 15;
    XT[id] = X[b * LL + n];
}

// ---------------- stage-1 K-split GEMM partials ----------------
// part[s][b][n] = sum_{m in split s} AT[m][b] * W[m][n]
// SINGLE-WAVE blocks (64 thr): fine-grained dispatch -> no per-CU block-count
// tail (the R9 residual). W2 grid = 2048 blocks = exactly 8/CU, zero tail.
// AT addresses thread-uniform -> scalar loads; W = coalesced nontemporal
// float2 stream (512B/wave-load); 32 reg accs; no LDS/barrier/atomics.
template <int CH, int NCOL>
__global__ __launch_bounds__(64, 8) void k_gpart(
        const float* __restrict__ AT,    // [KTOT][16]
        const float* __restrict__ W,     // [KTOT][NCOL]
        float* __restrict__ part) {      // [splits][16][NCOL]
    const int t  = threadIdx.x;
    const int n2 = blockIdx.x * 128 + t * 2;
    const int s  = blockIdx.y;
    const int m0 = s * CH;

    float2 acc[BB];
#pragma unroll
    for (int r = 0; r < BB; ++r) acc[r] = make_float2(0.f, 0.f);

    const float* wp = W  + (size_t)m0 * NCOL + n2;
    const float* ap = AT + (size_t)m0 * BB;
#pragma unroll 8
    for (int m = 0; m < CH; ++m) {
        const f32x2 w = __builtin_nontemporal_load((const f32x2*)wp); // nt stream
        wp += NCOL;
        const float4 a0 = *(const float4*)(ap + 0);   // uniform addr (SGPR)
        const float4 a1 = *(const float4*)(ap + 4);
        const float4 a2 = *(const float4*)(ap + 8);
        const float4 a3 = *(const float4*)(ap + 12);
        ap += BB;
        acc[ 0].x = fmaf(a0.x, w.x, acc[ 0].x);  acc[ 0].y = fmaf(a0.x, w.y, acc[ 0].y);
        acc[ 1].x = fmaf(a0.y, w.x, acc[ 1].x);  acc[ 1].y = fmaf(a0.y, w.y, acc[ 1].y);
        acc[ 2].x = fmaf(a0.z, w.x, acc[ 2].x);  acc[ 2].y = fmaf(a0.z, w.y, acc[ 2].y);
        acc[ 3].x = fmaf(a0.w, w.x, acc[ 3].x);  acc[ 3].y = fmaf(a0.w, w.y, acc[ 3].y);
        acc[ 4].x = fmaf(a1.x, w.x, acc[ 4].x);  acc[ 4].y = fmaf(a1.x, w.y, acc[ 4].y);
        acc[ 5].x = fmaf(a1.y, w.x, acc[ 5].x);  acc[ 5].y = fmaf(a1.y, w.y, acc[ 5].y);
        acc[ 6].x = fmaf(a1.z, w.x, acc[ 6].x);  acc[ 6].y = fmaf(a1.z, w.y, acc[ 6].y);
        acc[ 7].x = fmaf(a1.w, w.x, acc[ 7].x);  acc[ 7].y = fmaf(a1.w, w.y, acc[ 7].y);
        acc[ 8].x = fmaf(a2.x, w.x, acc[ 8].x);  acc[ 8].y = fmaf(a2.x, w.y, acc[ 8].y);
        acc[ 9].x = fmaf(a2.y, w.x, acc[ 9].x);  acc[ 9].y = fmaf(a2.y, w.y, acc[ 9].y);
        acc[10].x = fmaf(a2.z, w.x, acc[10].x);  acc[10].y = fmaf(a2.z, w.y, acc[10].y);
        acc[11].x = fmaf(a2.w, w.x, acc[11].x);  acc[11].y = fmaf(a2.w, w.y, acc[11].y);
        acc[12].x = fmaf(a3.x, w.x, acc[12].x);  acc[12].y = fmaf(a3.x, w.y, acc[12].y);
        acc[13].x = fmaf(a3.y, w.x, acc[13].x);  acc[13].y = fmaf(a3.y, w.y, acc[13].y);
        acc[14].x = fmaf(a3.z, w.x, acc[14].x);  acc[14].y = fmaf(a3.z, w.y, acc[14].y);
        acc[15].x = fmaf(a3.w, w.x, acc[15].x);  acc[15].y = fmaf(a3.w, w.y, acc[15].y);
    }

    float* pp = part + ((size_t)s * BB) * NCOL + n2;
#pragma unroll
    for (int r = 0; r < BB; ++r)
        *(float2*)(pp + (size_t)r * NCOL) = acc[r];   // plain stores (L2/L3 resident)
}

// ---------------- reduce splits, output TRANSPOSED [N][16] ----------------
// grid (N/256, 4): blockIdx.y picks a 4-row batch group -> 4x the blocks of
// the R9 version (fixes the 8-block issue-cap on the ypredT reduce).
template <bool SIG>
__global__ __launch_bounds__(256) void k_redT(
        const float* __restrict__ part,   // [splits][16][N]
        const float* __restrict__ bias,   // [N] or nullptr
        float* __restrict__ outT,         // [N][16]
        int N, int splits) {
    const int n  = blockIdx.x * 256 + threadIdx.x;
    const int b0 = blockIdx.y * 4;
    float acc[4] = {0.f, 0.f, 0.f, 0.f};
    for (int s = 0; s < splits; ++s) {
        const float* p = part + ((size_t)s * BB + b0) * N + n;
#pragma unroll
        for (int j = 0; j < 4; ++j) acc[j] += p[(size_t)j * N];   // coalesced
    }
    const float bv = bias ? bias[n] : 0.f;
#pragma unroll
    for (int j = 0; j < 4; ++j) {
        float v = acc[j] + bv;
        if (SIG) v = 1.f / (1.f + __expf(-v));
        acc[j] = v;
    }
    *(float4*)(outT + (size_t)n * BB + b0) = make_float4(acc[0], acc[1], acc[2], acc[3]);
}

// ---------------- reduce splits, natural layout [16][NN1] ----------------
__global__ __launch_bounds__(256) void k_redN(
        const float* __restrict__ part,   // [splits][16][NN1]; [s][b][n] at s*32768+id
        const float* __restrict__ bias,   // [NN1]
        float* __restrict__ out,          // [16][NN1]
        int splits) {
    const int id = blockIdx.x * 256 + threadIdx.x;   // 32768
    const int n  = id & (NN1 - 1);
    float acc[4] = {0.f, 0.f, 0.f, 0.f};
#pragma unroll 8
    for (int s = 0; s < splits; ++s)
        acc[s & 3] += part[(size_t)s * (BB * NN1) + id];
    out[id] = (acc[0] + acc[1]) + (acc[2] + acc[3]) + bias[n];
}

// out[b,i] = (1/L) * sum_j ( yr[j]*cos(2*pi*i*j/L) - yi[j]*sin(2*pi*i*j/L) )
// 4-way j-split: thread quarter jq does j = jq*256 .. jq*256+255; LDS combine.
__global__ __launch_bounds__(1024) void k_decode(const float* __restrict__ z2,
                                                 float* __restrict__ out) {
    __shared__ float yr[LL], yi[LL];
    __shared__ float partial[3 * 256];
    const int t  = threadIdx.x;
    const int b  = blockIdx.y;
    const int il = t & 255;
    const int i  = blockIdx.x * 256 + il;
    const int jq = t >> 8;                    // 0..3: j-quarter
    if (t < LL) {                             // t = 0..1023 exactly covers L
        yr[t] = z2[b * NN1 + t];
        yi[t] = z2[b * NN1 + LL + t];
    }
    __syncthreads();
    float acc = 0.f;
    int r = (jq * 256 * i) & (LL - 1);        // (i*j0) mod L, exact
    const int j0 = jq * 256;
    for (int jj = 0; jj < 256; ++jj) {
        float rev = (float)r * (1.0f / LL);   // revolutions in [0,1)
        float c = __builtin_amdgcn_cosf(rev); // v_cos_f32: cos(2*pi*rev)
        float s = __builtin_amdgcn_sinf(rev); // v_sin_f32: sin(2*pi*rev)
        acc = fmaf(yr[j0 + jj], c, acc);
        acc = fmaf(-yi[j0 + jj], s, acc);
        r = (r + i) & (LL - 1);
    }
    if (jq > 0) partial[(jq - 1) * 256 + il] = acc;
    __syncthreads();
    if (jq == 0)
        out[b * LL + i] = (acc + partial[il] + partial[256 + il] + partial[512 + il])
                          * (1.0f / LL);
}

extern "C" void kernel_launch(void* const* d_in, const int* in_sizes, int n_in,
                              void* d_out, int out_size, void* d_ws, size_t ws_size,
                              hipStream_t stream) {
    const float* X  = (const float*)d_in[0];
    const float* Fc = (const float*)d_in[1];
    const float* W1 = (const float*)d_in[2];
    const float* b1 = (const float*)d_in[3];
    const float* W2 = (const float*)d_in[4];
    const float* b2 = (const float*)d_in[5];
    float* out = (float*)d_out;

    // workspace layout (floats); every element is written before read each call
    float* ws     = (float*)d_ws;
    float* XT     = ws;                       //  1024*16      =    16384
    float* ypredT = XT     + LL * BB;         //  2048*16      =    32768
    float* hT     = ypredT + NN1 * BB;        // 51200*16      =   819200
    float* z2     = hT     + NNH * BB;        //    16*2048    =    32768
    float* parts0 = z2     + BB * NN1;        //  16*16*2048   =   524288
    float* parts1 = parts0 + 16 * BB * NN1;   //   8*16*51200  =  6553600
    float* parts2 = parts1 + 8 * BB * NNH;    // 128*16*2048   =  4194304
    // total ~12.2M floats = 49 MB

    // X^T
    k_xt<<<dim3(LL * BB / 256), 256, 0, stream>>>(X, XT);
    // y_pred^T = (X @ Fc)^T : CH=64, 16 splits, grid (16,16) = 256 single-wave blocks
    k_gpart<64, NN1><<<dim3(NN1 / 128, 16), 64, 0, stream>>>(XT, Fc, parts0);
    k_redT<false><<<dim3(NN1 / 256, 4), 256, 0, stream>>>(parts0, nullptr, ypredT, NN1, 16);
    // h^T = sigmoid(y_pred @ W1 + b1)^T : CH=256, 8 splits, grid (400,8) = 3200 blocks
    k_gpart<256, NNH><<<dim3(NNH / 128, 8), 64, 0, stream>>>(ypredT, W1, parts1);
    k_redT<true><<<dim3(NNH / 256, 4), 256, 0, stream>>>(parts1, b1, hT, NNH, 8);
    // z2 = h @ W2 + b2 : CH=400, 128 splits, grid (16,128) = 2048 blocks = 8/CU exact
    k_gpart<400, NN1><<<dim3(NN1 / 128, 128), 64, 0, stream>>>(hT, W2, parts2);
    k_redN<<<dim3(BB * NN1 / 256), 256, 0, stream>>>(parts2, b2, z2, 128);
    // decode (inverse-DFT form, exact mod-L phase; 4-way j-split)
    k_decode<<<dim3(LL / 256, BB), 1024, 0, stream>>>(z2, out);
}